// Round 8
// baseline (102.859 us; speedup 1.0000x reference)
//
#include <hip/hip_runtime.h>

// TwoStageRegressionLoss: fused BCE + duration-aware focal smooth-L1 mean
// reduction over N = 2048*16384 fp32 (4 input arrays, 537 MB read).
// History: R1 libm logf VALU-bound 77%. R2 hw __log2f -> 101us anchor.
// R3/R4 VGPR software pipelines -> compiler sank loads. R5 asm "=v" loads ->
// fault. R6 stream-split -> neutral (body not the limiter). R7 global_load_lds
// + 3-slot ring + counted vmcnt(2) -> 97.45us (WIN: drain theory confirmed).
// R8: (a) issue-early/wait-late (stage BEFORE the waitcnt, T14), (b) BUFS=4,
// 3 sets (6 loads) permanently in flight, WAITV(6), (c) LDS exactly 32768B
// (reduce reuses the ring) -> 5 blocks/CU fits 160KB exactly.

constexpr int BLOCK = 256;
constexpr int HGRID = 2048;        // blocks per loss half
constexpr int GRID  = 2 * HGRID;
constexpr int BUFS  = 4;           // ring slots: 1 consuming + 3 arriving

typedef float f32x4 __attribute__((ext_vector_type(4)));

// HW async DMA: lane l of the wave writes 16B to lds_base + l*16.
// global ptr is PER-LANE; LDS base must be wave-uniform (m97/m104).
__device__ __forceinline__ void stage16(const float* g, void* l) {
    __builtin_amdgcn_global_load_lds(
        (const __attribute__((address_space(1))) void*)g,
        (__attribute__((address_space(3))) void*)l,
        16, 0, 0);
}

#define WAITV(N) do { \
    asm volatile("s_waitcnt vmcnt(" #N ")" ::: "memory"); \
    __builtin_amdgcn_sched_barrier(0); \
} while (0)

__device__ __forceinline__ void bce_elem(float pv, float tv, float& acc) {
    // BCE in log2 domain: clamp(-100) in ln == clamp(-100/ln2) in log2.
    constexpr float CLAMP2 = -144.26950408889634f;
    float pc = fminf(fmaxf(pv, 0.0f), 1.0f);
    float tc = fminf(fmaxf(tv, 0.0f), 1.0f);
    float lp  = fmaxf(__log2f(pc),        CLAMP2);  // v_log_f32; log2(0)=-inf -> clamp
    float l1p = fmaxf(__log2f(1.0f - pc), CLAMP2);
    acc -= l1p + tc * (lp - l1p);   // == tc*lp + (1-tc)*l1p; *ln2 in final_kernel
}

__device__ __forceinline__ void focal_elem(float qv, float sv, float& acc) {
    // duration-aware focal smooth-L1 (alpha=0.25 applied in final_kernel)
    float d = fabsf(qv - sv);
    float f = fminf(d + d, 1.0f);                     // clip(d/0.5, 0, 1)
    float base = (d < 0.5f) ? (d * d) : (d - 0.25f);  // smooth L1, beta=0.5
    // class weight: round-half-even (jnp.round), clamp [0,3], table {1,4,3,2}
    float r = fminf(fmaxf(__builtin_rintf(sv), 0.0f), 3.0f);
    float w = (r == 0.0f) ? 1.0f : (r == 1.0f) ? 4.0f : (r == 2.0f) ? 3.0f : 2.0f;
    acc += (f * f) * base * w;
}

template <bool IS_BCE>
__device__ __forceinline__ void accum4(const f32x4& p, const f32x4& t,
                                       float& a0, float& a1) {
    if (IS_BCE) {
        bce_elem(p[0], t[0], a0); bce_elem(p[1], t[1], a1);
        bce_elem(p[2], t[2], a0); bce_elem(p[3], t[3], a1);
    } else {
        focal_elem(p[0], t[0], a0); focal_elem(p[1], t[1], a1);
        focal_elem(p[2], t[2], a0); focal_elem(p[3], t[3], a1);
    }
}

template <bool IS_BCE>
__device__ __forceinline__ void run_half(
    const f32x4* __restrict__ P, const f32x4* __restrict__ T,
    f32x4* smem, int vb, int n4, int n, float& a0, float& a1)
{
    const int tid    = (int)threadIdx.x;
    const int wid    = tid >> 6;
    const int stride = HGRID * BLOCK;           // in float4 units
    const int base   = vb * BLOCK + tid;
    const int iters  = n4 / stride;

    if ((n4 % stride) == 0 && iters >= BUFS) {
        // LDS: slot s, stream c -> smem[(s*2+c)*BLOCK + ...]; wave base +wid*64
        // prologue: stage sets 0,1,2 (6 loads in flight)
        #pragma unroll
        for (int d = 0; d < 3; ++d) {
            stage16((const float*)(P + base + (long)d * stride),
                    (void*)(smem + (d * 2 + 0) * BLOCK + wid * 64));
            stage16((const float*)(T + base + (long)d * stride),
                    (void*)(smem + (d * 2 + 1) * BLOCK + wid * 64));
        }
        for (int it = 0; it < iters; ++it) {
            const int slot = it & (BUFS - 1);
            // ---- issue-early: stage set it+3 BEFORE waiting (T14). ----
            // slot (it+3)%4 == (it-1)%4 was ds_read-consumed at iter it-1.
            if (it + 3 < iters) {
                const int s3 = (it + 3) & (BUFS - 1);
                stage16((const float*)(P + base + (long)(it + 3) * stride),
                        (void*)(smem + (s3 * 2 + 0) * BLOCK + wid * 64));
                stage16((const float*)(T + base + (long)(it + 3) * stride),
                        (void*)(smem + (s3 * 2 + 1) * BLOCK + wid * 64));
                WAITV(6);        // outstanding 8 -> oldest set (it) complete
            } else if (it + 3 == iters) {
                WAITV(4);        // outstanding 6, nothing staged this iter
            } else if (it + 2 == iters) {
                WAITV(2);        // outstanding 4
            } else {
                WAITV(0);        // last iteration: drain
            }
            f32x4 p = smem[(slot * 2 + 0) * BLOCK + tid];   // ds_read_b128
            f32x4 t = smem[(slot * 2 + 1) * BLOCK + tid];
            accum4<IS_BCE>(p, t, a0, a1);
        }
    } else {
        // generic fallback (R6 structure)
        for (int i = base; i < n4; i += stride) {
            f32x4 p = P[i];
            f32x4 t = T[i];
            accum4<IS_BCE>(p, t, a0, a1);
        }
        if (vb == 0) {  // scalar tail
            const float* Pf = (const float*)P;
            const float* Tf = (const float*)T;
            for (int k = n4 * 4 + tid; k < n; k += BLOCK) {
                if (IS_BCE) bce_elem(Pf[k], Tf[k], a0);
                else        focal_elem(Pf[k], Tf[k], a0);
            }
        }
    }
}

__global__ __launch_bounds__(BLOCK) void partial_kernel(
    const f32x4* __restrict__ bp4, const f32x4* __restrict__ rp4,
    const f32x4* __restrict__ bt4, const f32x4* __restrict__ rt4,
    float* __restrict__ partials, int n4, int n)
{
    // exactly 32768 B: 5 blocks/CU fits 160 KiB exactly (reduce reuses this)
    __shared__ f32x4 smem[BUFS * 2 * BLOCK];
    float a0 = 0.0f, a1 = 0.0f;
    const bool isB = (blockIdx.x < (unsigned)HGRID);
    const int  vb  = isB ? blockIdx.x : blockIdx.x - HGRID;

    if (isB) run_half<true >(bp4, bt4, smem, vb, n4, n, a0, a1);
    else     run_half<false>(rp4, rt4, smem, vb, n4, n, a0, a1);

    float acc = a0 + a1;
    // wave-64 reduce
    #pragma unroll
    for (int off = 32; off > 0; off >>= 1)
        acc += __shfl_down(acc, off, 64);
    // cross-wave reduce reusing the ring buffer as scratch
    float* sA = (float*)smem;
    const int lane = threadIdx.x & 63;
    const int wid  = threadIdx.x >> 6;
    __syncthreads();                  // all ds_reads of the ring complete
    if (lane == 0) sA[wid] = acc;
    __syncthreads();
    if (threadIdx.x == 0) {
        float v = 0.0f;
        #pragma unroll
        for (int w = 0; w < BLOCK / 64; ++w) v += sA[w];
        partials[blockIdx.x] = v;   // [0..HGRID) BCE sums, [HGRID..GRID) focal sums
    }
}

__global__ __launch_bounds__(BLOCK) void final_kernel(
    const float* __restrict__ partials, float* __restrict__ out, double invN)
{
    double accB = 0.0, accR = 0.0;
    for (int i = threadIdx.x; i < HGRID; i += BLOCK) {
        accB += (double)partials[i];
        accR += (double)partials[HGRID + i];
    }
    #pragma unroll
    for (int off = 32; off > 0; off >>= 1) {
        accB += __shfl_down(accB, off, 64);
        accR += __shfl_down(accR, off, 64);
    }
    __shared__ double dB[BLOCK / 64], dR[BLOCK / 64];
    const int lane = threadIdx.x & 63;
    const int wid  = threadIdx.x >> 6;
    if (lane == 0) { dB[wid] = accB; dR[wid] = accR; }
    __syncthreads();
    if (threadIdx.x == 0) {
        double b = 0.0, r = 0.0;
        #pragma unroll
        for (int w = 0; w < BLOCK / 64; ++w) { b += dB[w]; r += dR[w]; }
        const double bm = b * 0.6931471805599453 * invN;  // log2 -> ln
        const double rm = r * 0.25 * invN;                // alpha
        out[0] = (float)(bm + rm);  // total (BREAK_W = REG_W = 1)
        out[1] = (float)bm;         // break_loss
        out[2] = (float)rm;         // regression_loss
    }
}

extern "C" void kernel_launch(void* const* d_in, const int* in_sizes, int n_in,
                              void* d_out, int out_size, void* d_ws, size_t ws_size,
                              hipStream_t stream) {
    // setup_inputs() order: break_predictions, regression_predictions,
    //                       break_targets, regression_targets  (all fp32)
    const float* bp = (const float*)d_in[0];
    const float* rp = (const float*)d_in[1];
    const float* bt = (const float*)d_in[2];
    const float* rt = (const float*)d_in[3];
    const int n  = in_sizes[0];
    const int n4 = n / 4;
    float* partials = (float*)d_ws;   // GRID floats = 16 KB scratch

    partial_kernel<<<GRID, BLOCK, 0, stream>>>(
        (const f32x4*)bp, (const f32x4*)rp, (const f32x4*)bt, (const f32x4*)rt,
        partials, n4, n);
    final_kernel<<<1, BLOCK, 0, stream>>>(partials, (float*)d_out, 1.0 / (double)n);
}

// Round 9
// 100.699 us; speedup vs baseline: 1.0214x; 1.0214x over previous
//
#include <hip/hip_runtime.h>

// TwoStageRegressionLoss: fused BCE + duration-aware focal smooth-L1 mean
// reduction over N = 2048*16384 fp32 (4 input arrays, 537 MB read).
// History: R1 libm logf VALU-bound 77%. R2 hw __log2f -> 101us anchor.
// R3/R4 VGPR software pipelines -> compiler sank loads. R5 asm "=v" loads ->
// fault. R6 stream-split -> neutral. R7 global_load_lds 3-slot ring +
// counted vmcnt(2) -> 97.45us WIN (occ 59%, 6 blocks/CU). R8 BUFS=4 + 32KB
// LDS -> occupancy 38%, 102.9us FAIL (TLP > per-wave depth).
// R9: R7 geometry EXACTLY (BUFS=3, 24KB, 6 blocks/CU) + issue-early/wait-late
// only: stage set it+2 BEFORE the counted wait -> 6 loads outstanding during
// the wait window instead of 4. Single-variable isolation of T14.

constexpr int BLOCK = 256;
constexpr int HGRID = 2048;        // blocks per loss half
constexpr int GRID  = 2 * HGRID;
constexpr int BUFS  = 3;           // ring slots (R7 geometry)

typedef float f32x4 __attribute__((ext_vector_type(4)));

// HW async DMA: lane l of the wave writes 16B to lds_base + l*16.
// global ptr is PER-LANE; LDS base must be wave-uniform (m97/m104).
__device__ __forceinline__ void stage16(const float* g, void* l) {
    __builtin_amdgcn_global_load_lds(
        (const __attribute__((address_space(1))) void*)g,
        (__attribute__((address_space(3))) void*)l,
        16, 0, 0);
}

#define WAITV(N) do { \
    asm volatile("s_waitcnt vmcnt(" #N ")" ::: "memory"); \
    __builtin_amdgcn_sched_barrier(0); \
} while (0)

__device__ __forceinline__ void bce_elem(float pv, float tv, float& acc) {
    // BCE in log2 domain: clamp(-100) in ln == clamp(-100/ln2) in log2.
    constexpr float CLAMP2 = -144.26950408889634f;
    float pc = fminf(fmaxf(pv, 0.0f), 1.0f);
    float tc = fminf(fmaxf(tv, 0.0f), 1.0f);
    float lp  = fmaxf(__log2f(pc),        CLAMP2);  // v_log_f32; log2(0)=-inf -> clamp
    float l1p = fmaxf(__log2f(1.0f - pc), CLAMP2);
    acc -= l1p + tc * (lp - l1p);   // == tc*lp + (1-tc)*l1p; *ln2 in final_kernel
}

__device__ __forceinline__ void focal_elem(float qv, float sv, float& acc) {
    // duration-aware focal smooth-L1 (alpha=0.25 applied in final_kernel)
    float d = fabsf(qv - sv);
    float f = fminf(d + d, 1.0f);                     // clip(d/0.5, 0, 1)
    float base = (d < 0.5f) ? (d * d) : (d - 0.25f);  // smooth L1, beta=0.5
    // class weight: round-half-even (jnp.round), clamp [0,3], table {1,4,3,2}
    float r = fminf(fmaxf(__builtin_rintf(sv), 0.0f), 3.0f);
    float w = (r == 0.0f) ? 1.0f : (r == 1.0f) ? 4.0f : (r == 2.0f) ? 3.0f : 2.0f;
    acc += (f * f) * base * w;
}

template <bool IS_BCE>
__device__ __forceinline__ void accum4(const f32x4& p, const f32x4& t,
                                       float& a0, float& a1) {
    if (IS_BCE) {
        bce_elem(p[0], t[0], a0); bce_elem(p[1], t[1], a1);
        bce_elem(p[2], t[2], a0); bce_elem(p[3], t[3], a1);
    } else {
        focal_elem(p[0], t[0], a0); focal_elem(p[1], t[1], a1);
        focal_elem(p[2], t[2], a0); focal_elem(p[3], t[3], a1);
    }
}

template <bool IS_BCE>
__device__ __forceinline__ void run_half(
    const f32x4* __restrict__ P, const f32x4* __restrict__ T,
    f32x4* smem, int vb, int n4, int n, float& a0, float& a1)
{
    const int tid    = (int)threadIdx.x;
    const int wid    = tid >> 6;
    const int stride = HGRID * BLOCK;           // in float4 units
    const int base   = vb * BLOCK + tid;
    const int iters  = n4 / stride;

    if ((n4 % stride) == 0 && iters >= BUFS) {
        // LDS: slot s, stream c -> smem[(s*2+c)*BLOCK + ...]; wave base +wid*64
        // prologue: stage sets 0,1 (4 loads in flight)
        #pragma unroll
        for (int d = 0; d < 2; ++d) {
            stage16((const float*)(P + base + (long)d * stride),
                    (void*)(smem + (d * 2 + 0) * BLOCK + wid * 64));
            stage16((const float*)(T + base + (long)d * stride),
                    (void*)(smem + (d * 2 + 1) * BLOCK + wid * 64));
        }
        for (int it = 0; it < iters; ++it) {
            const int slot = it % BUFS;
            // ---- issue-early (T14): stage set it+2 BEFORE the wait, so the
            // wait window holds 6 outstanding loads, not 4. Slot (it+2)%3 ==
            // (it-1)%3 was register-consumed at iteration it-1 -> no hazard.
            if (it + 2 < iters) {
                const int s2 = (it + 2) % BUFS;
                stage16((const float*)(P + base + (long)(it + 2) * stride),
                        (void*)(smem + (s2 * 2 + 0) * BLOCK + wid * 64));
                stage16((const float*)(T + base + (long)(it + 2) * stride),
                        (void*)(smem + (s2 * 2 + 1) * BLOCK + wid * 64));
                WAITV(4);        // 6 outstanding -> oldest set (it) complete
            } else if (it + 2 == iters) {
                WAITV(2);        // 4 outstanding, nothing staged this iter
            } else {
                WAITV(0);        // last iteration: drain
            }
            f32x4 p = smem[(slot * 2 + 0) * BLOCK + tid];   // ds_read_b128
            f32x4 t = smem[(slot * 2 + 1) * BLOCK + tid];
            accum4<IS_BCE>(p, t, a0, a1);
        }
    } else {
        // generic fallback (R6 structure)
        for (int i = base; i < n4; i += stride) {
            f32x4 p = P[i];
            f32x4 t = T[i];
            accum4<IS_BCE>(p, t, a0, a1);
        }
        if (vb == 0) {  // scalar tail
            const float* Pf = (const float*)P;
            const float* Tf = (const float*)T;
            for (int k = n4 * 4 + tid; k < n; k += BLOCK) {
                if (IS_BCE) bce_elem(Pf[k], Tf[k], a0);
                else        focal_elem(Pf[k], Tf[k], a0);
            }
        }
    }
}

__global__ __launch_bounds__(BLOCK) void partial_kernel(
    const f32x4* __restrict__ bp4, const f32x4* __restrict__ rp4,
    const f32x4* __restrict__ bt4, const f32x4* __restrict__ rt4,
    float* __restrict__ partials, int n4, int n)
{
    __shared__ f32x4 smem[BUFS * 2 * BLOCK];   // 24 KB -> 6 blocks/CU (R7)
    float a0 = 0.0f, a1 = 0.0f;
    const bool isB = (blockIdx.x < (unsigned)HGRID);
    const int  vb  = isB ? blockIdx.x : blockIdx.x - HGRID;

    if (isB) run_half<true >(bp4, bt4, smem, vb, n4, n, a0, a1);
    else     run_half<false>(rp4, rt4, smem, vb, n4, n, a0, a1);

    float acc = a0 + a1;
    // wave-64 reduce
    #pragma unroll
    for (int off = 32; off > 0; off >>= 1)
        acc += __shfl_down(acc, off, 64);
    __shared__ float sA[BLOCK / 64];
    const int lane = threadIdx.x & 63;
    const int wid  = threadIdx.x >> 6;
    if (lane == 0) sA[wid] = acc;
    __syncthreads();
    if (threadIdx.x == 0) {
        float v = 0.0f;
        #pragma unroll
        for (int w = 0; w < BLOCK / 64; ++w) v += sA[w];
        partials[blockIdx.x] = v;   // [0..HGRID) BCE sums, [HGRID..GRID) focal sums
    }
}

__global__ __launch_bounds__(BLOCK) void final_kernel(
    const float* __restrict__ partials, float* __restrict__ out, double invN)
{
    double accB = 0.0, accR = 0.0;
    for (int i = threadIdx.x; i < HGRID; i += BLOCK) {
        accB += (double)partials[i];
        accR += (double)partials[HGRID + i];
    }
    #pragma unroll
    for (int off = 32; off > 0; off >>= 1) {
        accB += __shfl_down(accB, off, 64);
        accR += __shfl_down(accR, off, 64);
    }
    __shared__ double dB[BLOCK / 64], dR[BLOCK / 64];
    const int lane = threadIdx.x & 63;
    const int wid  = threadIdx.x >> 6;
    if (lane == 0) { dB[wid] = accB; dR[wid] = accR; }
    __syncthreads();
    if (threadIdx.x == 0) {
        double b = 0.0, r = 0.0;
        #pragma unroll
        for (int w = 0; w < BLOCK / 64; ++w) { b += dB[w]; r += dR[w]; }
        const double bm = b * 0.6931471805599453 * invN;  // log2 -> ln
        const double rm = r * 0.25 * invN;                // alpha
        out[0] = (float)(bm + rm);  // total (BREAK_W = REG_W = 1)
        out[1] = (float)bm;         // break_loss
        out[2] = (float)rm;         // regression_loss
    }
}

extern "C" void kernel_launch(void* const* d_in, const int* in_sizes, int n_in,
                              void* d_out, int out_size, void* d_ws, size_t ws_size,
                              hipStream_t stream) {
    // setup_inputs() order: break_predictions, regression_predictions,
    //                       break_targets, regression_targets  (all fp32)
    const float* bp = (const float*)d_in[0];
    const float* rp = (const float*)d_in[1];
    const float* bt = (const float*)d_in[2];
    const float* rt = (const float*)d_in[3];
    const int n  = in_sizes[0];
    const int n4 = n / 4;
    float* partials = (float*)d_ws;   // GRID floats = 16 KB scratch

    partial_kernel<<<GRID, BLOCK, 0, stream>>>(
        (const f32x4*)bp, (const f32x4*)rp, (const f32x4*)bt, (const f32x4*)rt,
        partials, n4, n);
    final_kernel<<<1, BLOCK, 0, stream>>>(partials, (float*)d_out, 1.0 / (double)n);
}